// Round 9
// baseline (408.413 us; speedup 1.0000x reference)
//
#include <hip/hip_runtime.h>
#include <hip/hip_fp16.h>

// Affinity propagation, [X=256,Y=256,Z=32] fp32, 3 iterations x 3 dirs.
//
// R9 = R7 structure (fp16 weights precomputed once, transposed [dir][z][x][y];
// each iteration's 3 steps fused in one kernel via LDS halo) with iter3
// re-tiled for occupancy: 8x8 tile (region 12x12 = 144 cols), 192 threads,
// 1024 blocks, LDS 38 KB -> 4 blocks/CU (12 waves/CU vs R8's 8).
// Scalar LDS access, CSTR=33 (conflict-free); R8 proved vectorization neutral.
// OOB semantics ride on weights==0 across edges; LDS zero-init keeps z-edge
// reads benign (always multiplied by 0).

constexpr int NV = 256 * 256 * 32;   // 2097152
constexpr int YZ = 256 * 32;         // 8192
constexpr int NG = NV / 4;
constexpr int GEND = 24 * NV;

constexpr int TB = 8;                // output tile 8x8
constexpr int R = 12;                // region 12x12 (halo 2)
constexpr int NCOL = R * R;          // 144 columns
constexpr int CSTR = 33;             // column stride (odd => conflict-free)
constexpr int LOFF = 16;             // guard for z-1 / far-column reads
constexpr int LSZ = NCOL * CSTR + 2 * LOFF;   // 4784 floats = 19.1 KB

struct alignas(16) H8 { __half2 h[4]; };   // 8 fp16 weights per voxel

__device__ __forceinline__ int iclamp(int v, int lo, int hi) {
    return min(max(v, lo), hi);
}

// ---------------- weight precompute (transposed store) ----------------
template <int DIR>
__device__ __forceinline__ void wgroup_t(int f0, const float* __restrict__ g,
                                         H8* __restrict__ wt) {
    constexpr int d1[8] = {1, 1, 1, 0, 0, -1, -1, -1};
    constexpr int d2[8] = {1, 0, -1, 1, -1, 1, 0, -1};
    const int z = f0 & 31, y = (f0 >> 5) & 255, x = f0 >> 13;
    const int gb0 = DIR * 8 * NV;

    float G[8][4];

    if (DIR == 0) {
#pragma unroll
        for (int k = 0; k < 8; ++k) {
            const int a = x + d1[k], b = y + d2[k];
            const bool valid = ((unsigned)a < 256u) & ((unsigned)b < 256u);
            const int ofs = f0 + d1[k] * YZ + d2[k] * 32;
            float4 gv = *(const float4*)(g + iclamp(gb0 + k * NV + ofs, 0, GEND - 4));
            if (!valid) { gv.x = 0.f; gv.y = 0.f; gv.z = 0.f; gv.w = 0.f; }
            G[k][0] = gv.x; G[k][1] = gv.y; G[k][2] = gv.z; G[k][3] = gv.w;
        }
    } else {
        const int s1 = (DIR == 1) ? YZ : 32;
        const int c1 = (DIR == 1) ? x : y;
        const bool zlo = (z > 0), zhi = (z < 28);
#pragma unroll
        for (int k = 0; k < 8; ++k) {
            const bool vrow = (unsigned)(c1 + d1[k]) < 256u;
            const int gb = gb0 + k * NV + f0 + d1[k] * s1;
            float4 gv = *(const float4*)(g + iclamp(gb, 0, GEND - 4));
            if (!vrow) { gv.x = 0.f; gv.y = 0.f; gv.z = 0.f; gv.w = 0.f; }
            if (d2[k] == 1) {
                float ge = g[iclamp(gb + 4, 0, GEND - 1)];
                ge = (vrow && zhi) ? ge : 0.f;
                G[k][0] = gv.y; G[k][1] = gv.z; G[k][2] = gv.w; G[k][3] = ge;
            } else if (d2[k] == -1) {
                float ge = g[iclamp(gb - 1, 0, GEND - 1)];
                ge = (vrow && zlo) ? ge : 0.f;
                G[k][0] = ge; G[k][1] = gv.x; G[k][2] = gv.y; G[k][3] = gv.z;
            } else {
                G[k][0] = gv.x; G[k][1] = gv.y; G[k][2] = gv.z; G[k][3] = gv.w;
            }
        }
    }

#pragma unroll
    for (int i = 0; i < 4; ++i) {
        float asum = 0.f;
#pragma unroll
        for (int k = 0; k < 8; ++k) asum += fabsf(G[k][i]);
        const float winv = __builtin_amdgcn_rcpf(asum);
        H8 rec;
#pragma unroll
        for (int p = 0; p < 4; ++p)
            rec.h[p] = __floats2half2_rn(G[2 * p][i] * winv, G[2 * p + 1][i] * winv);
        const int zz = (f0 + i) & 31;
        wt[((DIR * 32 + zz) << 16) + (x << 8) + y] = rec;
    }
}

__global__ __launch_bounds__(256) void make_w(const float* __restrict__ g,
                                              H8* __restrict__ wt) {
    const int b = blockIdx.x;
    const int dir = b >> 11;                 // 2048 blocks per dir
    const int f0 = ((b & 2047) * 256 + threadIdx.x) << 2;
    if (dir == 0)      wgroup_t<0>(f0, g, wt);
    else if (dir == 1) wgroup_t<1>(f0, g, wt);
    else               wgroup_t<2>(f0, g, wt);
}

// ---------------- fused 3-step (one iteration) kernel ----------------
template <int DIR, bool STORE>
__device__ __forceinline__ void fstep(const H8* __restrict__ wt,
                                      const float* __restrict__ src,  // LDS
                                      float* __restrict__ dst,        // LDS (!STORE)
                                      float* __restrict__ gq,         // global (STORE)
                                      int cb, int gxc, int gyc, bool in) {
    if (!in) return;
    const int wb = ((DIR * 32) << 16) + (gxc << 8) + gyc;
#pragma unroll 8
    for (int z = 0; z < 32; ++z) {
        const H8 wr = wt[wb + (z << 16)];
        float w[8]; float2 f;
        f = __half22float2(wr.h[0]); w[0] = f.x; w[1] = f.y;
        f = __half22float2(wr.h[1]); w[2] = f.x; w[3] = f.y;
        f = __half22float2(wr.h[2]); w[4] = f.x; w[5] = f.y;
        f = __half22float2(wr.h[3]); w[6] = f.x; w[7] = f.y;
        const float rc = src[cb + z];
        float a = rc;
        if (DIR == 0) {              // (x+-1, y+-1), same z
            a = fmaf(w[0], src[cb + z + (R + 1) * CSTR] - rc, a);
            a = fmaf(w[1], src[cb + z +  R      * CSTR] - rc, a);
            a = fmaf(w[2], src[cb + z + (R - 1) * CSTR] - rc, a);
            a = fmaf(w[3], src[cb + z +           CSTR] - rc, a);
            a = fmaf(w[4], src[cb + z -           CSTR] - rc, a);
            a = fmaf(w[5], src[cb + z - (R - 1) * CSTR] - rc, a);
            a = fmaf(w[6], src[cb + z -  R      * CSTR] - rc, a);
            a = fmaf(w[7], src[cb + z - (R + 1) * CSTR] - rc, a);
        } else if (DIR == 1) {       // (x+-1, z+-1)
            a = fmaf(w[0], src[cb + z + 1 + R * CSTR] - rc, a);
            a = fmaf(w[1], src[cb + z     + R * CSTR] - rc, a);
            a = fmaf(w[2], src[cb + z - 1 + R * CSTR] - rc, a);
            a = fmaf(w[3], src[cb + z + 1] - rc, a);
            a = fmaf(w[4], src[cb + z - 1] - rc, a);
            a = fmaf(w[5], src[cb + z + 1 - R * CSTR] - rc, a);
            a = fmaf(w[6], src[cb + z     - R * CSTR] - rc, a);
            a = fmaf(w[7], src[cb + z - 1 - R * CSTR] - rc, a);
        } else {                     // (y+-1, z+-1)
            a = fmaf(w[0], src[cb + z + 1 + CSTR] - rc, a);
            a = fmaf(w[1], src[cb + z     + CSTR] - rc, a);
            a = fmaf(w[2], src[cb + z - 1 + CSTR] - rc, a);
            a = fmaf(w[3], src[cb + z + 1] - rc, a);
            a = fmaf(w[4], src[cb + z - 1] - rc, a);
            a = fmaf(w[5], src[cb + z + 1 - CSTR] - rc, a);
            a = fmaf(w[6], src[cb + z     - CSTR] - rc, a);
            a = fmaf(w[7], src[cb + z - 1 - CSTR] - rc, a);
        }
        if (STORE) gq[z] = a;
        else       dst[cb + z] = a;
    }
}

__global__ __launch_bounds__(192) void iter3(const H8* __restrict__ wt,
                                             const float* __restrict__ rin,
                                             float* __restrict__ rout) {
    __shared__ float A[LSZ];
    __shared__ float B[LSZ];
    const int t  = threadIdx.x;
    const int bx = blockIdx.x & 31, by = blockIdx.x >> 5;  // 32 x 32 blocks
    const bool act = t < NCOL;
    const int rx = t / R, ry = t - rx * R;
    const int gx = bx * TB - 2 + rx, gy = by * TB - 2 + ry;
    const int gxc = iclamp(gx, 0, 255), gyc = iclamp(gy, 0, 255);
    const int cb = t * CSTR + LOFF;

    for (int i = t; i < LSZ; i += 192) { A[i] = 0.f; B[i] = 0.f; }
    __syncthreads();
    if (act) {
        const float* p = rin + ((gxc << 8) + gyc) * 32;
#pragma unroll
        for (int j = 0; j < 8; ++j) {
            const float4 v = *(const float4*)(p + 4 * j);
            A[cb + 4 * j]     = v.x; A[cb + 4 * j + 1] = v.y;
            A[cb + 4 * j + 2] = v.z; A[cb + 4 * j + 3] = v.w;
        }
    }
    __syncthreads();

    const bool in0 = act && rx >= 1 && rx <= R - 2 && ry >= 1 && ry <= R - 2;
    const bool in1 = act && rx >= 2 && rx <= R - 3 && ry >= 1 && ry <= R - 2;
    const bool in2 = act && rx >= 2 && rx <= R - 3 && ry >= 2 && ry <= R - 3;

    fstep<0, false>(wt, A, B, nullptr, cb, gxc, gyc, in0);
    __syncthreads();
    fstep<1, false>(wt, B, A, nullptr, cb, gxc, gyc, in1);
    __syncthreads();
    float* gq = rout + ((gx << 8) + gy) * 32;   // in2 => gx,gy in-volume
    fstep<2, true>(wt, A, nullptr, gq, cb, gxc, gyc, in2);
}

// ---------------- fallback (R1-proven): direct-from-guidance steps ----------------
template <int DIR>
__global__ __launch_bounds__(256) void prop_step(const float* __restrict__ g,
                                                 const float* __restrict__ rin,
                                                 float* __restrict__ rout) {
    constexpr int d1[8] = {1, 1, 1, 0, 0, -1, -1, -1};
    constexpr int d2[8] = {1, 0, -1, 1, -1, 1, 0, -1};
    const int t = blockIdx.x * 256 + threadIdx.x;
    const int f0 = t << 2;
    const int z = f0 & 31, y = (f0 >> 5) & 255, x = f0 >> 13;
    const int gb0 = DIR * 8 * NV;

    float as[4] = {0, 0, 0, 0}, ac[4] = {0, 0, 0, 0};
    float4 rc;

    if (DIR == 0) {
        rc = *(const float4*)(rin + f0);
#pragma unroll
        for (int k = 0; k < 8; ++k) {
            const int a = x + d1[k], b = y + d2[k];
            const bool valid = ((unsigned)a < 256u) & ((unsigned)b < 256u);
            const int ofs = f0 + d1[k] * YZ + d2[k] * 32;
            const float4 rv = *(const float4*)(rin + iclamp(ofs, 0, NV - 4));
            float4 gv = *(const float4*)(g + iclamp(gb0 + k * NV + ofs, 0, GEND - 4));
            if (!valid) { gv.x = 0.f; gv.y = 0.f; gv.z = 0.f; gv.w = 0.f; }
            as[0] += fabsf(gv.x); as[1] += fabsf(gv.y);
            as[2] += fabsf(gv.z); as[3] += fabsf(gv.w);
            ac[0] = fmaf(gv.x, rv.x - rc.x, ac[0]); ac[1] = fmaf(gv.y, rv.y - rc.y, ac[1]);
            ac[2] = fmaf(gv.z, rv.z - rc.z, ac[2]); ac[3] = fmaf(gv.w, rv.w - rc.w, ac[3]);
        }
    } else {
        const int s1 = (DIR == 1) ? YZ : 32;
        const int c1 = (DIR == 1) ? x : y;
        float4 rv[3]; float rl[3], rr[3];
#pragma unroll
        for (int j = 0; j < 3; ++j) {
            const int ro = f0 + (1 - j) * s1;
            rv[j] = *(const float4*)(rin + iclamp(ro, 0, NV - 4));
            rl[j] = rin[iclamp(ro - 1, 0, NV - 1)];
            rr[j] = rin[iclamp(ro + 4, 0, NV - 1)];
        }
        rc = rv[1];
        const bool zlo = (z > 0), zhi = (z < 28);
#pragma unroll
        for (int k = 0; k < 8; ++k) {
            const int j = 1 - d1[k];
            const bool vrow = (unsigned)(c1 + d1[k]) < 256u;
            const int gb = gb0 + k * NV + f0 + d1[k] * s1;
            float4 gv = *(const float4*)(g + iclamp(gb, 0, GEND - 4));
            if (!vrow) { gv.x = 0.f; gv.y = 0.f; gv.z = 0.f; gv.w = 0.f; }
            float4 gk, rk;
            if (d2[k] == 1) {
                float ge = g[iclamp(gb + 4, 0, GEND - 1)];
                ge = (vrow && zhi) ? ge : 0.f;
                gk = make_float4(gv.y, gv.z, gv.w, ge);
                rk = make_float4(rv[j].y, rv[j].z, rv[j].w, rr[j]);
            } else if (d2[k] == -1) {
                float ge = g[iclamp(gb - 1, 0, GEND - 1)];
                ge = (vrow && zlo) ? ge : 0.f;
                gk = make_float4(ge, gv.x, gv.y, gv.z);
                rk = make_float4(rl[j], rv[j].x, rv[j].y, rv[j].z);
            } else {
                gk = gv; rk = rv[j];
            }
            as[0] += fabsf(gk.x); as[1] += fabsf(gk.y);
            as[2] += fabsf(gk.z); as[3] += fabsf(gk.w);
            ac[0] = fmaf(gk.x, rk.x - rc.x, ac[0]); ac[1] = fmaf(gk.y, rk.y - rc.y, ac[1]);
            ac[2] = fmaf(gk.z, rk.z - rc.z, ac[2]); ac[3] = fmaf(gk.w, rk.w - rc.w, ac[3]);
        }
    }

    float4 o;
    o.x = rc.x + ac[0] * __builtin_amdgcn_rcpf(as[0]);
    o.y = rc.y + ac[1] * __builtin_amdgcn_rcpf(as[1]);
    o.z = rc.z + ac[2] * __builtin_amdgcn_rcpf(as[2]);
    o.w = rc.w + ac[3] * __builtin_amdgcn_rcpf(as[3]);
    *(float4*)(rout + f0) = o;
}

extern "C" void kernel_launch(void* const* d_in, const int* in_sizes, int n_in,
                              void* d_out, int out_size, void* d_ws, size_t ws_size,
                              hipStream_t stream) {
    const float* g    = (const float*)d_in[0];
    const float* blur = (const float*)d_in[1];
    float* out = (float*)d_out;

    const size_t WBYTES = (size_t)3 * NV * sizeof(H8);            // 96 MiB
    const size_t NEED   = WBYTES + (size_t)2 * NV * sizeof(float);

    if (ws_size >= NEED) {
        H8*    wt   = (H8*)d_ws;
        float* bufA = (float*)((char*)d_ws + WBYTES);
        float* bufB = bufA + NV;

        make_w<<<dim3(3 * NG / 256), dim3(256), 0, stream>>>(g, wt);
        iter3<<<dim3(1024), dim3(192), 0, stream>>>(wt, blur, bufA);
        iter3<<<dim3(1024), dim3(192), 0, stream>>>(wt, bufA, bufB);
        iter3<<<dim3(1024), dim3(192), 0, stream>>>(wt, bufB, out);
    } else {
        // fallback: R1-proven direct path (needs only 8 MiB of ws)
        float* ws = (float*)d_ws;
        const dim3 block(256), sgrid(NG / 256);
        const float* src = blur;
        for (int step = 0; step < 9; ++step) {
            float* dst = (step & 1) ? ws : out;
            switch (step % 3) {
                case 0: prop_step<0><<<sgrid, block, 0, stream>>>(g, src, dst); break;
                case 1: prop_step<1><<<sgrid, block, 0, stream>>>(g, src, dst); break;
                case 2: prop_step<2><<<sgrid, block, 0, stream>>>(g, src, dst); break;
            }
            src = dst;
        }
    }
}